// Round 1
// baseline (109.062 us; speedup 1.0000x reference)
//
#include <hip/hip_runtime.h>

#define FR 3
#define KS 7
#define TILE 32
#define HALO (TILE + 2*FR)   // 38
#define LSTR 40              // LDS row stride (floats)
#define IMG_H 512
#define IMG_W 512
#define NB 8
#define NC 3

__device__ __forceinline__ int refl(int i, int n) {
    i = (i < 0) ? -i : i;
    return (i >= n) ? (2*n - 2 - i) : i;
}

__global__ __launch_bounds__(256) void blt_kernel(const float* __restrict__ in,
                                                  float* __restrict__ ws) {
    __shared__ float sm[NC][HALO][LSTR];   // 3*38*40*4 = 18240 B
    __shared__ float wsum[4];
    const int bx  = blockIdx.x * TILE;
    const int by  = blockIdx.y * TILE;
    const int b   = blockIdx.z;
    const int tx  = threadIdx.x;
    const int tid = threadIdx.y * 32 + tx;
    const float* base = in + (size_t)b * NC * IMG_H * IMG_W;

    // Stage 38x38 halo tile for 3 channels, reflect-padded at image borders.
    for (int idx = tid; idx < HALO * HALO; idx += 256) {
        int ly = idx / HALO;
        int lx = idx - ly * HALO;
        int gy = refl(by + ly - FR, IMG_H);
        int gx = refl(bx + lx - FR, IMG_W);
        #pragma unroll
        for (int c = 0; c < NC; ++c)
            sm[c][ly][lx] = base[(c * IMG_H + gy) * IMG_W + gx];
    }
    __syncthreads();

    // Gaussian weights: computed in double (like numpy), cast to float,
    // fully constant-folded at compile time in the unrolled loop below.
    constexpr double g0 = 0.011108996538242306;  // exp(-4.5)
    constexpr double g1 = 0.1353352832366127;    // exp(-2.0)
    constexpr double g2 = 0.6065306597126334;    // exp(-0.5)
    constexpr double g1d[7] = {g0, g1, g2, 1.0, g2, g1, g0};
    constexpr double SUMG = 1.0 + 2.0 * (g0 + g1 + g2);
    constexpr double INVS = 1.0 / (SUMG * SUMG);

    float acc = 0.0f;
    #pragma unroll
    for (int i = 0; i < 4; ++i) {
        const int py = threadIdx.y + 8 * i;   // pixel row within tile
        const float c0 = sm[0][py + FR][tx + FR];
        const float c1 = sm[1][py + FR][tx + FR];
        const float c2 = sm[2][py + FR][tx + FR];
        #pragma unroll
        for (int k = 0; k < KS; ++k) {
            #pragma unroll
            for (int l = 0; l < KS; ++l) {
                if (k == FR && l == FR) continue;   // center tap: d==0 -> contributes 0
                const float wg = (float)(g1d[k] * g1d[l] * INVS);
                float v0 = sm[0][py + k][tx + l];
                float v1 = sm[1][py + k][tx + l];
                float v2 = sm[2][py + k][tx + l];
                float d0 = c0 - v0, d1 = c1 - v1, d2 = c2 - v2;
                float s  = d0 * d0 + d1 * d1 + d2 * d2;
                float w  = __expf(s * -50.0f) * wg;   // 1/(2*0.1^2) = 50
                acc += (fabsf(d0) + fabsf(d1) + fabsf(d2)) * w;
            }
        }
    }

    // 64-lane wave reduce, then cross-wave via LDS, then one atomic per block.
    #pragma unroll
    for (int off = 32; off > 0; off >>= 1)
        acc += __shfl_down(acc, off, 64);
    const int lane = tid & 63, wid = tid >> 6;
    if (lane == 0) wsum[wid] = acc;
    __syncthreads();
    if (tid == 0)
        atomicAdd(ws, wsum[0] + wsum[1] + wsum[2] + wsum[3]);
}

__global__ void finalize_kernel(const float* __restrict__ ws, float* __restrict__ out) {
    out[0] = ws[0] / (float)(NB * NC * IMG_H * IMG_W);
}

extern "C" void kernel_launch(void* const* d_in, const int* in_sizes, int n_in,
                              void* d_out, int out_size, void* d_ws, size_t ws_size,
                              hipStream_t stream) {
    const float* in = (const float*)d_in[0];
    float* out = (float*)d_out;
    float* ws  = (float*)d_ws;

    hipMemsetAsync(ws, 0, sizeof(float), stream);   // harness poisons d_ws each call

    dim3 grid(IMG_W / TILE, IMG_H / TILE, NB);      // 16 x 16 x 8 = 2048 blocks
    dim3 block(32, 8);
    blt_kernel<<<grid, block, 0, stream>>>(in, ws);
    finalize_kernel<<<1, 1, 0, stream>>>(ws, out);
}

// Round 2
// 107.203 us; speedup vs baseline: 1.0173x; 1.0173x over previous
//
#include <hip/hip_runtime.h>

#define FR 3
#define KS 7
#define TLX 64
#define TLY 16
#define PPT 4              // consecutive pixel rows per thread
#define HX (TLX + 2*FR)    // 70
#define HY (TLY + 2*FR)    // 22
#define LSTR 72            // LDS row stride (floats)
#define IMG_H 512
#define IMG_W 512
#define NB 8
#define NC 3
#define GX (IMG_W / TLX)   // 8
#define GY (IMG_H / TLY)   // 32
#define NBLK (GX * GY * NB) // 2048

// exp(-50*s) = 2^(-K2*s), K2 = 50*log2(e). Pre-scale inputs by K=sqrt(K2) so the
// exp argument is just the (negated) sum of squared diffs of scaled values.
#define KSC 8.493218f      // sqrt(72.13475204444817), K^2 accurate to ~6e-10 rel

__device__ __forceinline__ int refl(int i, int n) {
    i = (i < 0) ? -i : i;
    return (i >= n) ? (2*n - 2 - i) : i;
}

__global__ __launch_bounds__(256) void blt_kernel(const float* __restrict__ in,
                                                  float* __restrict__ partial) {
    __shared__ float sm[NC][HY][LSTR];   // 3*22*72*4 = 19008 B
    __shared__ float gtab[8];
    __shared__ float wsum[4];

    // Gaussian pieces in double (matches numpy path), folded to float constants.
    constexpr double g0 = 0.011108996538242306;  // exp(-4.5)
    constexpr double g1 = 0.1353352832366127;    // exp(-2.0)
    constexpr double g2 = 0.6065306597126334;    // exp(-0.5)
    constexpr double SUMG = 1.0 + 2.0 * (g0 + g1 + g2);
    constexpr double KD   = 8.493218;            // must match KSC
    // per-column constant: g1d[l] / (SUMG^2 * K)  (1/K un-scales |d'|)
    const float glc[KS] = {
        (float)(g0 / (SUMG * SUMG * KD)), (float)(g1 / (SUMG * SUMG * KD)),
        (float)(g2 / (SUMG * SUMG * KD)), (float)(1.0 / (SUMG * SUMG * KD)),
        (float)(g2 / (SUMG * SUMG * KD)), (float)(g1 / (SUMG * SUMG * KD)),
        (float)(g0 / (SUMG * SUMG * KD))
    };

    const int bx  = blockIdx.x * TLX;
    const int by  = blockIdx.y * TLY;
    const int b   = blockIdx.z;
    const int tx  = threadIdx.x;               // 0..63 (one wave per ty row)
    const int ty  = threadIdx.y;               // 0..3
    const int tid = ty * 64 + tx;
    const float* base = in + (size_t)b * NC * IMG_H * IMG_W;

    if (tid == 0) {
        gtab[0] = (float)g0; gtab[1] = (float)g1; gtab[2] = (float)g2;
        gtab[3] = 1.0f;      gtab[4] = (float)g2; gtab[5] = (float)g1;
        gtab[6] = (float)g0;
    }

    // Stage reflect-padded halo tile, pre-scaled by K.
    for (int idx = tid; idx < HY * HX; idx += 256) {
        int ly = idx / HX;
        int lx = idx - ly * HX;
        int gy = refl(by + ly - FR, IMG_H);
        int gx = refl(bx + lx - FR, IMG_W);
        #pragma unroll
        for (int c = 0; c < NC; ++c)
            sm[c][ly][lx] = base[(c * IMG_H + gy) * IMG_W + gx] * KSC;
    }
    __syncthreads();

    const int r0 = ty * PPT;   // strip's first pixel row (tile coords); halo rows r0..r0+9
    float c0[PPT], c1[PPT], c2[PPT], acc[PPT];
    #pragma unroll
    for (int i = 0; i < PPT; ++i) {
        c0[i] = sm[0][r0 + i + FR][tx + FR];
        c1[i] = sm[1][r0 + i + FR][tx + FR];
        c2[i] = sm[2][r0 + i + FR][tx + FR];
        acc[i] = 0.0f;
    }

    // Each halo row is read once (21 values) and reused by up to 4 pixels.
    #pragma unroll 1
    for (int r = 0; r < PPT + KS - 1; ++r) {   // 10 rows
        const int hr = r0 + r;
        float v0[KS], v1[KS], v2[KS];
        #pragma unroll
        for (int l = 0; l < KS; ++l) {
            v0[l] = sm[0][hr][tx + l];
            v1[l] = sm[1][hr][tx + l];
            v2[l] = sm[2][hr][tx + l];
        }
        #pragma unroll
        for (int i = 0; i < PPT; ++i) {
            const int k = r - i;               // tap row for pixel i (uniform branch)
            if (k < 0 || k >= KS) continue;
            float t = 0.0f;
            #pragma unroll
            for (int l = 0; l < KS; ++l) {
                float d0 = c0[i] - v0[l];
                float d1 = c1[i] - v1[l];
                float d2 = c2[i] - v2[l];
                float s = d0 * d0;
                s = fmaf(d1, d1, s);
                s = fmaf(d2, d2, s);
                float e = __builtin_amdgcn_exp2f(-s);   // exp(-50*sum d^2)
                float sa = fabsf(d0) + fabsf(d1);
                sa += fabsf(d2);
                t = fmaf(sa, e * glc[l], t);            // center tap adds exactly 0
            }
            acc[i] = fmaf(t, gtab[k], acc[i]);
        }
    }

    float a = acc[0] + acc[1] + acc[2] + acc[3];
    #pragma unroll
    for (int off = 32; off > 0; off >>= 1)
        a += __shfl_down(a, off, 64);
    if ((tid & 63) == 0) wsum[tid >> 6] = a;
    __syncthreads();
    if (tid == 0) {
        int bid = blockIdx.x + GX * (blockIdx.y + GY * blockIdx.z);
        partial[bid] = wsum[0] + wsum[1] + wsum[2] + wsum[3];
    }
}

__global__ __launch_bounds__(256) void finalize_kernel(const float* __restrict__ partial,
                                                       float* __restrict__ out) {
    __shared__ float wsum[4];
    const int tid = threadIdx.x;
    float a = 0.0f;
    for (int i = tid; i < NBLK; i += 256) a += partial[i];
    #pragma unroll
    for (int off = 32; off > 0; off >>= 1)
        a += __shfl_down(a, off, 64);
    if ((tid & 63) == 0) wsum[tid >> 6] = a;
    __syncthreads();
    if (tid == 0)
        out[0] = (wsum[0] + wsum[1] + wsum[2] + wsum[3]) / (float)(NB * NC * IMG_H * IMG_W);
}

extern "C" void kernel_launch(void* const* d_in, const int* in_sizes, int n_in,
                              void* d_out, int out_size, void* d_ws, size_t ws_size,
                              hipStream_t stream) {
    const float* in = (const float*)d_in[0];
    float* out = (float*)d_out;
    float* ws  = (float*)d_ws;      // 2048 partials; every slot written each call

    dim3 grid(GX, GY, NB);          // 8 x 32 x 8 = 2048 blocks = 8/CU, fully resident
    dim3 block(TLX, 256 / TLX);     // (64,4)
    blt_kernel<<<grid, block, 0, stream>>>(in, ws);
    finalize_kernel<<<1, 256, 0, stream>>>(ws, out);
}

// Round 3
// 98.487 us; speedup vs baseline: 1.1074x; 1.0885x over previous
//
#include <hip/hip_runtime.h>

#define FR 3
#define KS 7
#define TLX 64
#define TLY 16
#define PPT 4                 // consecutive pixel rows per thread
#define HX (TLX + 2*FR)       // 70 (left+right halo)
#define HY (TLY + FR)         // 19 (top halo only; half-kernel has dy<=0)
#define LSTR 72               // LDS row stride (floats)
#define IMG_H 512
#define IMG_W 512
#define NB 8
#define NC 3
#define GXB (IMG_W / TLX)     // 8
#define GYB (IMG_H / TLY)     // 32
#define NMAIN (GXB * GYB * NB)    // 2048
#define RIM_PER_IMG 6108          // 512^2 - 506^2
#define NRIM_THREADS (RIM_PER_IMG * NB)          // 48864
#define NRIM_BLK ((NRIM_THREADS + 255) / 256)    // 191
#define NPART (NMAIN + NRIM_BLK)                 // 2239

// exp(-50*s) = 2^(-K2*s), K2 = 50*log2(e)=72.13475204444817. Main kernel
// pre-scales inputs by K=sqrt(K2) so exp2 arg is just -(sum of squared diffs).
#define KSC 8.493218f
#define K2F 72.134752f

// Gaussian pieces in double (matches numpy float64 path), folded to constants.
constexpr double g1d[KS] = {0.011108996538242306, 0.1353352832366127,
                            0.6065306597126334,   1.0,
                            0.6065306597126334,   0.1353352832366127,
                            0.011108996538242306};
constexpr double SUMG = 1.0 + 2.0 * (0.011108996538242306 + 0.1353352832366127
                                     + 0.6065306597126334);
constexpr double INVN = 1.0 / (SUMG * SUMG);
constexpr double KD   = 8.493218;   // must match KSC

__device__ __forceinline__ int refl(int i, int n) {
    i = (i < 0) ? -i : i;
    return (i >= n) ? (2*n - 2 - i) : i;
}

// ---- main kernel: paired (doubled) half-kernel taps, partner in-image only ----
__global__ __launch_bounds__(256) void blt_main(const float* __restrict__ in,
                                                float* __restrict__ partial) {
    __shared__ float sm[NC][HY][LSTR];   // 3*19*72*4 = 16416 B
    __shared__ float wsum[4];

    const int bx  = blockIdx.x * TLX;
    const int by  = blockIdx.y * TLY;
    const int b   = blockIdx.z;
    const int tx  = threadIdx.x;         // 0..63
    const int ty  = threadIdx.y;         // 0..3
    const int tid = ty * 64 + tx;
    const float* base = in + (size_t)b * NC * IMG_H * IMG_W;

    // Stage top/side reflect-padded halo tile, pre-scaled by K.
    for (int idx = tid; idx < HY * HX; idx += 256) {
        int ly = idx / HX;
        int lx = idx - ly * HX;
        int gy = refl(by + ly - FR, IMG_H);
        int gx = refl(bx + lx - FR, IMG_W);
        #pragma unroll
        for (int c = 0; c < NC; ++c)
            sm[c][ly][lx] = base[(c * IMG_H + gy) * IMG_W + gx] * KSC;
    }
    __syncthreads();

    // Per-thread masked column weights: glm[l] = partner-col-in-image ? 2*g1d[l]/(SUMG^2*K) : 0
    float glm[KS];
    #pragma unroll
    for (int l = 0; l < KS; ++l) {
        bool inx = (unsigned)(bx + tx + l - FR) < (unsigned)IMG_W;
        glm[l] = inx ? (float)(2.0 * g1d[l] * INVN / KD) : 0.0f;
    }

    const int r0 = ty * PPT;    // strip's first pixel row in tile
    // Row mask: partner row (by + r0 + rr - 3) >= 0  (only top image rows fail)
    float gym[KS];
    #pragma unroll
    for (int rr = 0; rr < KS; ++rr)
        gym[rr] = (by + r0 + rr - FR >= 0) ? 1.0f : 0.0f;

    float c0[PPT], c1[PPT], c2[PPT], acc[PPT];
    #pragma unroll
    for (int i = 0; i < PPT; ++i) {
        c0[i] = sm[0][r0 + i + FR][tx + FR];
        c1[i] = sm[1][r0 + i + FR][tx + FR];
        c2[i] = sm[2][r0 + i + FR][tx + FR];
        acc[i] = 0.0f;
    }

    // Halo rows r0-3..r0+3 -> sm rows r0+rr, rr=0..6. Pixel i uses rr in [i, i+3];
    // rr-i==3 is the dy==0 row (left taps only).
    #pragma unroll
    for (int rr = 0; rr < KS; ++rr) {
        float v0[KS], v1[KS], v2[KS];
        #pragma unroll
        for (int l = 0; l < KS; ++l) {
            v0[l] = sm[0][r0 + rr][tx + l];
            v1[l] = sm[1][r0 + rr][tx + l];
            v2[l] = sm[2][r0 + rr][tx + l];
        }
        #pragma unroll
        for (int i = 0; i < PPT; ++i) {
            const int k = rr - i;            // = dy + 3
            if (k < 0 || k > FR) continue;   // compile-time
            const int lmax = (k == FR) ? FR : KS;   // dy==0: l<3 only
            float t = 0.0f;
            #pragma unroll
            for (int l = 0; l < 7; ++l) {
                if (l >= lmax) continue;     // compile-time
                float d0 = c0[i] - v0[l];
                float d1 = c1[i] - v1[l];
                float d2 = c2[i] - v2[l];
                float s = d0 * d0;
                s = fmaf(d1, d1, s);
                s = fmaf(d2, d2, s);
                float e = __builtin_amdgcn_exp2f(-s);
                float sa = fabsf(d0) + fabsf(d1);
                sa += fabsf(d2);
                t = fmaf(sa, e * glm[l], t);
            }
            acc[i] = fmaf(t, (float)g1d[k] * gym[rr], acc[i]);
        }
    }

    float a = acc[0] + acc[1] + acc[2] + acc[3];
    #pragma unroll
    for (int off = 32; off > 0; off >>= 1)
        a += __shfl_down(a, off, 64);
    if ((tid & 63) == 0) wsum[tid >> 6] = a;
    __syncthreads();
    if (tid == 0) {
        int bid = blockIdx.x + GXB * (blockIdx.y + GYB * blockIdx.z);
        partial[bid] = wsum[0] + wsum[1] + wsum[2] + wsum[3];
    }
}

// ---- rim kernel: all taps whose partner is out-of-image (reflected), counted once ----
__global__ __launch_bounds__(256) void blt_rim(const float* __restrict__ in,
                                               float* __restrict__ partial) {
    __shared__ float wsum[4];
    const int tid = threadIdx.x;
    const int idx = blockIdx.x * 256 + tid;
    float a = 0.0f;
    if (idx < NRIM_THREADS) {
        const int b = idx / RIM_PER_IMG;
        int r = idx - b * RIM_PER_IMG;
        int y, x;
        if (r < 3 * IMG_W) { y = r >> 9; x = r & (IMG_W - 1); }
        else if (r < 6 * IMG_W) { r -= 3 * IMG_W; y = (IMG_H - 3) + (r >> 9); x = r & (IMG_W - 1); }
        else if (r < 6 * IMG_W + 3 * (IMG_H - 6)) { r -= 6 * IMG_W; y = 3 + r / 3; x = r - 3 * (r / 3); }
        else { r -= 6 * IMG_W + 3 * (IMG_H - 6); y = 3 + r / 3; x = (IMG_W - 3) + (r - 3 * (r / 3)); }

        const float* base = in + (size_t)b * NC * IMG_H * IMG_W;
        const float cc0 = base[(0 * IMG_H + y) * IMG_W + x];
        const float cc1 = base[(1 * IMG_H + y) * IMG_W + x];
        const float cc2 = base[(2 * IMG_H + y) * IMG_W + x];

        #pragma unroll
        for (int k = 0; k < KS; ++k) {
            #pragma unroll
            for (int l = 0; l < KS; ++l) {
                if (k == FR && l == FR) continue;
                const int dy = k - FR, dx = l - FR;
                int qy = y + dy, qx = x + dx;
                bool oob = ((unsigned)qy >= (unsigned)IMG_H) | ((unsigned)qx >= (unsigned)IMG_W);
                if (oob) {
                    int ry = refl(qy, IMG_H), rx = refl(qx, IMG_W);
                    float v0 = base[(0 * IMG_H + ry) * IMG_W + rx];
                    float v1 = base[(1 * IMG_H + ry) * IMG_W + rx];
                    float v2 = base[(2 * IMG_H + ry) * IMG_W + rx];
                    float d0 = cc0 - v0, d1 = cc1 - v1, d2 = cc2 - v2;
                    float s = d0 * d0;
                    s = fmaf(d1, d1, s);
                    s = fmaf(d2, d2, s);
                    float e = __builtin_amdgcn_exp2f(-(K2F * s));
                    float sa = fabsf(d0) + fabsf(d1) + fabsf(d2);
                    a = fmaf(sa, e * (float)(g1d[k] * g1d[l] * INVN), a);
                }
            }
        }
    }
    #pragma unroll
    for (int off = 32; off > 0; off >>= 1)
        a += __shfl_down(a, off, 64);
    if ((tid & 63) == 0) wsum[tid >> 6] = a;
    __syncthreads();
    if (tid == 0) partial[NMAIN + blockIdx.x] = wsum[0] + wsum[1] + wsum[2] + wsum[3];
}

__global__ __launch_bounds__(256) void finalize_kernel(const float* __restrict__ partial,
                                                       float* __restrict__ out) {
    __shared__ float wsum[4];
    const int tid = threadIdx.x;
    float a = 0.0f;
    for (int i = tid; i < NPART; i += 256) a += partial[i];
    #pragma unroll
    for (int off = 32; off > 0; off >>= 1)
        a += __shfl_down(a, off, 64);
    if ((tid & 63) == 0) wsum[tid >> 6] = a;
    __syncthreads();
    if (tid == 0)
        out[0] = (wsum[0] + wsum[1] + wsum[2] + wsum[3]) / (float)(NB * NC * IMG_H * IMG_W);
}

extern "C" void kernel_launch(void* const* d_in, const int* in_sizes, int n_in,
                              void* d_out, int out_size, void* d_ws, size_t ws_size,
                              hipStream_t stream) {
    const float* in = (const float*)d_in[0];
    float* out = (float*)d_out;
    float* ws  = (float*)d_ws;      // NPART partials; every slot written each call

    dim3 grid(GXB, GYB, NB);        // 8 x 32 x 8 = 2048 blocks
    dim3 block(TLX, 256 / TLX);     // (64,4)
    blt_main<<<grid, block, 0, stream>>>(in, ws);
    blt_rim<<<NRIM_BLK, 256, 0, stream>>>(in, ws);
    finalize_kernel<<<1, 256, 0, stream>>>(ws, out);
}

// Round 4
// 94.726 us; speedup vs baseline: 1.1513x; 1.0397x over previous
//
#include <hip/hip_runtime.h>

#define FR 3
#define KS 7
#define TLX 128
#define TLY 16
#define PPT 4                 // consecutive pixel rows per thread
#define PPX 2                 // consecutive pixel cols per thread
#define HX (TLX + 2*FR)       // 134
#define HY (TLY + FR)         // 19 (top halo only; half-kernel has dy<=0)
#define LSTR 136              // LDS row stride (floats), 8B-aligned rows
#define IMG_H 512
#define IMG_W 512
#define NB 8
#define NC 3
#define GXB (IMG_W / TLX)     // 4
#define GYB (IMG_H / TLY)     // 32
#define NMAIN (GXB * GYB * NB)    // 1024
#define RIM_PER_IMG 6108          // 512^2 - 506^2
#define NRIM_THREADS (RIM_PER_IMG * NB)          // 48864
#define NRIM_BLK ((NRIM_THREADS + 255) / 256)    // 191
#define NBLK_A (NMAIN + NRIM_BLK)                // 1215
#define NPART NBLK_A

// exp(-50*s) = 2^(-K2*s), K2 = 50*log2(e)=72.13475204444817. Main kernel
// pre-scales inputs by K=sqrt(K2) so exp2 arg is just -(sum of squared diffs).
#define KSC 8.493218f
#define K2F 72.134752f

constexpr double g1d[KS] = {0.011108996538242306, 0.1353352832366127,
                            0.6065306597126334,   1.0,
                            0.6065306597126334,   0.1353352832366127,
                            0.011108996538242306};
constexpr double SUMG = 1.0 + 2.0 * (0.011108996538242306 + 0.1353352832366127
                                     + 0.6065306597126334);
constexpr double INVN = 1.0 / (SUMG * SUMG);
constexpr double KD   = 8.493218;   // must match KSC
constexpr double WPAIR = 2.0 * INVN / KD;   // pair-doubled, un-scaled, normalized

__device__ __forceinline__ int refl(int i, int n) {
    i = (i < 0) ? -i : i;
    return (i >= n) ? (2*n - 2 - i) : i;
}

// Fused kernel: blocks [0,NMAIN) = paired half-kernel interior taps;
// blocks [NMAIN,NBLK_A) = rim (OOB-partner taps, reflected, counted once).
__global__ __launch_bounds__(256) void blt_fused(const float* __restrict__ in,
                                                 float* __restrict__ partial) {
    __shared__ float sm[NC][HY][LSTR];   // 3*19*136*4 = 31008 B
    __shared__ float wsum[4];
    const int tid = threadIdx.x;
    float a = 0.0f;

    if (blockIdx.x < NMAIN) {
        // ---- main path ----
        const int bid = blockIdx.x;
        const int b   = bid >> 7;            // 128 blocks per image (4 x 32)
        const int rem = bid & 127;
        const int by  = (rem >> 2) * TLY;
        const int bx  = (rem & 3) * TLX;
        const int tx  = tid & 63;            // 0..63 -> pixel pair columns
        const int ty  = tid >> 6;            // 0..3  -> 4-row strip
        const float* base = in + (size_t)b * NC * IMG_H * IMG_W;

        // Stage reflect-padded halo tile (top+side), pre-scaled by K.
        for (int idx = tid; idx < HY * HX; idx += 256) {
            int ly = idx / HX;
            int lx = idx - ly * HX;
            int gy = refl(by + ly - FR, IMG_H);
            int gx = refl(bx + lx - FR, IMG_W);
            #pragma unroll
            for (int c = 0; c < NC; ++c)
                sm[c][ly][lx] = base[(c * IMG_H + gy) * IMG_W + gx] * KSC;
        }
        __syncthreads();

        // Per-pixel-column masked weights: 2*g1d[l]*INVN/KD if partner col in-image.
        const int x0 = bx + 2 * tx;          // pixel0 global x; pixel1 = x0+1
        float glm0[KS], glm1[KS];
        #pragma unroll
        for (int l = 0; l < KS; ++l) {
            glm0[l] = ((unsigned)(x0 + l - FR)     < (unsigned)IMG_W) ? (float)(g1d[l] * WPAIR) : 0.0f;
            glm1[l] = ((unsigned)(x0 + 1 + l - FR) < (unsigned)IMG_W) ? (float)(g1d[l] * WPAIR) : 0.0f;
        }

        const int r0 = ty * PPT;             // strip's first pixel row in tile
        float cc0[PPT][PPX], cc1[PPT][PPX], cc2[PPT][PPX];
        float acc0 = 0.0f, acc1 = 0.0f;

        // Descending rows: pixel-row i's center row (rr=i+3) is visited first,
        // so centers are captured from the window registers (no extra reads).
        #pragma unroll
        for (int rr = KS - 1; rr >= 0; --rr) {
            float w0[8], w1[8], w2[8];
            #pragma unroll
            for (int j = 0; j < 4; ++j) {    // 8-float window = 4 x ds_read_b64
                float2 t0 = *reinterpret_cast<const float2*>(&sm[0][r0 + rr][2 * tx + 2 * j]);
                float2 t1 = *reinterpret_cast<const float2*>(&sm[1][r0 + rr][2 * tx + 2 * j]);
                float2 t2 = *reinterpret_cast<const float2*>(&sm[2][r0 + rr][2 * tx + 2 * j]);
                w0[2*j] = t0.x; w0[2*j+1] = t0.y;
                w1[2*j] = t1.x; w1[2*j+1] = t1.y;
                w2[2*j] = t2.x; w2[2*j+1] = t2.y;
            }
            #pragma unroll
            for (int i = 0; i < PPT; ++i) {
                const int k = rr - i;                 // dy + 3
                if (k < 0 || k > FR) continue;        // compile-time
                if (k == FR) {                        // center row: capture centers
                    cc0[i][0] = w0[3]; cc0[i][1] = w0[4];
                    cc1[i][0] = w1[3]; cc1[i][1] = w1[4];
                    cc2[i][0] = w2[3]; cc2[i][1] = w2[4];
                }
                const int lmax = (k == FR) ? FR : KS; // dy==0: left cols only
                // Row factor: g1d[k] if partner row in-image (only top rows fail).
                const float rw = (by + r0 + i + k >= FR) ? (float)g1d[k] : 0.0f;
                float t0 = 0.0f, t1 = 0.0f;
                #pragma unroll
                for (int l = 0; l < KS; ++l) {
                    if (l >= lmax) continue;          // compile-time
                    // pixel 0: window w[l]
                    {
                        float d0 = cc0[i][0] - w0[l];
                        float d1 = cc1[i][0] - w1[l];
                        float d2 = cc2[i][0] - w2[l];
                        float s = d0 * d0;
                        s = fmaf(d1, d1, s);
                        s = fmaf(d2, d2, s);
                        float e = __builtin_amdgcn_exp2f(-s);
                        float sa = fabsf(d0) + fabsf(d1);
                        sa += fabsf(d2);
                        t0 = fmaf(sa, e * glm0[l], t0);
                    }
                    // pixel 1: window w[l+1]
                    {
                        float d0 = cc0[i][1] - w0[l + 1];
                        float d1 = cc1[i][1] - w1[l + 1];
                        float d2 = cc2[i][1] - w2[l + 1];
                        float s = d0 * d0;
                        s = fmaf(d1, d1, s);
                        s = fmaf(d2, d2, s);
                        float e = __builtin_amdgcn_exp2f(-s);
                        float sa = fabsf(d0) + fabsf(d1);
                        sa += fabsf(d2);
                        t1 = fmaf(sa, e * glm1[l], t1);
                    }
                }
                acc0 = fmaf(t0, rw, acc0);
                acc1 = fmaf(t1, rw, acc1);
            }
        }
        a = acc0 + acc1;
    } else {
        // ---- rim path: taps whose partner is out-of-image, counted once ----
        const int idx = (blockIdx.x - NMAIN) * 256 + tid;
        if (idx < NRIM_THREADS) {
            const int b = idx / RIM_PER_IMG;
            int r = idx - b * RIM_PER_IMG;
            int y, x;
            if (r < 3 * IMG_W) { y = r >> 9; x = r & (IMG_W - 1); }
            else if (r < 6 * IMG_W) { r -= 3 * IMG_W; y = (IMG_H - 3) + (r >> 9); x = r & (IMG_W - 1); }
            else if (r < 6 * IMG_W + 3 * (IMG_H - 6)) { r -= 6 * IMG_W; y = 3 + r / 3; x = r - 3 * (r / 3); }
            else { r -= 6 * IMG_W + 3 * (IMG_H - 6); y = 3 + r / 3; x = (IMG_W - 3) + (r - 3 * (r / 3)); }

            const float* base = in + (size_t)b * NC * IMG_H * IMG_W;
            const float cc0 = base[(0 * IMG_H + y) * IMG_W + x];
            const float cc1 = base[(1 * IMG_H + y) * IMG_W + x];
            const float cc2 = base[(2 * IMG_H + y) * IMG_W + x];

            #pragma unroll
            for (int k = 0; k < KS; ++k) {
                #pragma unroll
                for (int l = 0; l < KS; ++l) {
                    if (k == FR && l == FR) continue;
                    int qy = y + k - FR, qx = x + l - FR;
                    bool oob = ((unsigned)qy >= (unsigned)IMG_H) | ((unsigned)qx >= (unsigned)IMG_W);
                    if (oob) {
                        int ry = refl(qy, IMG_H), rx = refl(qx, IMG_W);
                        float v0 = base[(0 * IMG_H + ry) * IMG_W + rx];
                        float v1 = base[(1 * IMG_H + ry) * IMG_W + rx];
                        float v2 = base[(2 * IMG_H + ry) * IMG_W + rx];
                        float d0 = cc0 - v0, d1 = cc1 - v1, d2 = cc2 - v2;
                        float s = d0 * d0;
                        s = fmaf(d1, d1, s);
                        s = fmaf(d2, d2, s);
                        float e = __builtin_amdgcn_exp2f(-(K2F * s));
                        float sa = fabsf(d0) + fabsf(d1) + fabsf(d2);
                        a = fmaf(sa, e * (float)(g1d[k] * g1d[l] * INVN), a);
                    }
                }
            }
        }
        __syncthreads();   // match main path's barrier count (uniform per block anyway)
    }

    // Block reduction -> one partial per block.
    #pragma unroll
    for (int off = 32; off > 0; off >>= 1)
        a += __shfl_down(a, off, 64);
    if ((tid & 63) == 0) wsum[tid >> 6] = a;
    __syncthreads();
    if (tid == 0)
        partial[blockIdx.x] = wsum[0] + wsum[1] + wsum[2] + wsum[3];
}

__global__ __launch_bounds__(256) void finalize_kernel(const float* __restrict__ partial,
                                                       float* __restrict__ out) {
    __shared__ float wsum[4];
    const int tid = threadIdx.x;
    float a = 0.0f;
    for (int i = tid; i < NPART; i += 256) a += partial[i];
    #pragma unroll
    for (int off = 32; off > 0; off >>= 1)
        a += __shfl_down(a, off, 64);
    if ((tid & 63) == 0) wsum[tid >> 6] = a;
    __syncthreads();
    if (tid == 0)
        out[0] = (wsum[0] + wsum[1] + wsum[2] + wsum[3]) / (float)(NB * NC * IMG_H * IMG_W);
}

extern "C" void kernel_launch(void* const* d_in, const int* in_sizes, int n_in,
                              void* d_out, int out_size, void* d_ws, size_t ws_size,
                              hipStream_t stream) {
    const float* in = (const float*)d_in[0];
    float* out = (float*)d_out;
    float* ws  = (float*)d_ws;      // NPART partials; every slot written each call

    blt_fused<<<NBLK_A, 256, 0, stream>>>(in, ws);
    finalize_kernel<<<1, 256, 0, stream>>>(ws, out);
}

// Round 5
// 94.403 us; speedup vs baseline: 1.1553x; 1.0034x over previous
//
#include <hip/hip_runtime.h>

#define FR 3
#define KS 7
#define TLX 128
#define TLY 16
#define PPT 4                 // consecutive pixel rows per thread
#define HX (TLX + 2*FR)       // 134
#define HY (TLY + FR)         // 19 (top halo only; half-kernel has dy<=0)
#define LSTR 136              // LDS row stride (floats), 8B-aligned rows
#define IMG_H 512
#define IMG_W 512
#define NB 8
#define NC 3
#define GXB (IMG_W / TLX)     // 4
#define GYB (IMG_H / TLY)     // 32
#define NMAIN (GXB * GYB * NB)    // 1024
#define RIM_PER_IMG 6108          // 512^2 - 506^2
#define NRIM_THREADS (RIM_PER_IMG * NB)          // 48864
#define NRIM_BLK ((NRIM_THREADS + 255) / 256)    // 191
#define NBLK_A (NMAIN + NRIM_BLK)                // 1215
#define NPART NBLK_A

// exp(-50*s) = 2^(-K2*s), K2 = 50*log2(e)=72.13475204444817. Main kernel
// pre-scales inputs by K=sqrt(K2) so exp2 arg is just -(sum of squared diffs).
#define KSC 8.493218f
#define K2F 72.134752f

typedef float v2f __attribute__((ext_vector_type(2)));
__device__ __forceinline__ v2f mk2(float a, float b) { v2f r; r.x = a; r.y = b; return r; }

constexpr double g1d[KS] = {0.011108996538242306, 0.1353352832366127,
                            0.6065306597126334,   1.0,
                            0.6065306597126334,   0.1353352832366127,
                            0.011108996538242306};
constexpr double SUMG = 1.0 + 2.0 * (0.011108996538242306 + 0.1353352832366127
                                     + 0.6065306597126334);
constexpr double INVN = 1.0 / (SUMG * SUMG);
constexpr double KD   = 8.493218;   // must match KSC
constexpr double WPAIR = 2.0 * INVN / KD;   // pair-doubled, un-scaled, normalized

__device__ __forceinline__ int refl(int i, int n) {
    i = (i < 0) ? -i : i;
    return (i >= n) ? (2*n - 2 - i) : i;
}

// Fused kernel. Blocks [0, NRIM_BLK) = rim path (scattered, latency-bound) —
// scheduled FIRST so they hide under the main blocks instead of forming a tail.
// Blocks [NRIM_BLK, NBLK_A) = main path: paired half-kernel interior taps.
__global__ __launch_bounds__(256) void blt_fused(const float* __restrict__ in,
                                                 float* __restrict__ partial) {
    __shared__ float sm[NC][HY][LSTR];   // 3*19*136*4 = 31008 B
    __shared__ float wsum[4];
    const int tid = threadIdx.x;
    float a = 0.0f;

    if (blockIdx.x >= NRIM_BLK) {
        // ---- main path ----
        const int bid = blockIdx.x - NRIM_BLK;
        const int b   = bid >> 7;            // 128 blocks per image (4 x 32)
        const int rem = bid & 127;
        const int by  = (rem >> 2) * TLY;
        const int bx  = (rem & 3) * TLX;
        const int tx  = tid & 63;            // pixel pair column index
        const int ty  = tid >> 6;            // 0..3 -> 4-row strip
        const float* base = in + (size_t)b * NC * IMG_H * IMG_W;

        // Stage reflect-padded halo tile (top+side), pre-scaled by K.
        for (int idx = tid; idx < HY * HX; idx += 256) {
            int ly = idx / HX;
            int lx = idx - ly * HX;
            int gy = refl(by + ly - FR, IMG_H);
            int gx = refl(bx + lx - FR, IMG_W);
            #pragma unroll
            for (int c = 0; c < NC; ++c)
                sm[c][ly][lx] = base[(c * IMG_H + gy) * IMG_W + gx] * KSC;
        }
        __syncthreads();

        // Per-pixel-column masked weights, packed: {pixel0, pixel1} per l.
        const int x0 = bx + 2 * tx;
        v2f glmv[KS];
        #pragma unroll
        for (int l = 0; l < KS; ++l) {
            float m0 = ((unsigned)(x0 + l - FR)     < (unsigned)IMG_W) ? (float)(g1d[l] * WPAIR) : 0.0f;
            float m1 = ((unsigned)(x0 + 1 + l - FR) < (unsigned)IMG_W) ? (float)(g1d[l] * WPAIR) : 0.0f;
            glmv[l] = mk2(m0, m1);
        }

        const int r0 = ty * PPT;
        v2f ccv[PPT][NC];
        v2f acc[PPT];
        #pragma unroll
        for (int i = 0; i < PPT; ++i) acc[i] = mk2(0.0f, 0.0f);

        // Descending halo rows: pixel-row i's center row (rr=i+3) comes first,
        // so centers are captured from the row window (no extra reads).
        #pragma unroll
        for (int rr = KS - 1; rr >= 0; --rr) {
            // Row window w[0..7] per channel as 4 aligned float2 (ds_read_b64),
            // then the 7 shifted pairs {w[l], w[l+1]}.
            v2f wp[NC][KS];
            #pragma unroll
            for (int c = 0; c < NC; ++c) {
                v2f p0 = *reinterpret_cast<const v2f*>(&sm[c][r0 + rr][2 * tx + 0]);
                v2f p1 = *reinterpret_cast<const v2f*>(&sm[c][r0 + rr][2 * tx + 2]);
                v2f p2 = *reinterpret_cast<const v2f*>(&sm[c][r0 + rr][2 * tx + 4]);
                v2f p3 = *reinterpret_cast<const v2f*>(&sm[c][r0 + rr][2 * tx + 6]);
                wp[c][0] = p0;
                wp[c][1] = mk2(p0.y, p1.x);
                wp[c][2] = p1;
                wp[c][3] = mk2(p1.y, p2.x);
                wp[c][4] = p2;
                wp[c][5] = mk2(p2.y, p3.x);
                wp[c][6] = p3;
            }
            #pragma unroll
            for (int i = 0; i < PPT; ++i) {
                const int k = rr - i;                 // dy + 3
                if (k < 0 || k > FR) continue;        // compile-time
                if (k == FR) {                        // center row: capture centers
                    ccv[i][0] = wp[0][3];
                    ccv[i][1] = wp[1][3];
                    ccv[i][2] = wp[2][3];
                }
                const int lmax = (k == FR) ? FR : KS; // dy==0: left cols only
                // Row factor: g1d[k] if partner row in-image (only top rows fail).
                const float rw = (by + r0 + rr >= FR) ? (float)g1d[k] : 0.0f;
                v2f t = mk2(0.0f, 0.0f);
                #pragma unroll
                for (int l = 0; l < KS; ++l) {
                    if (l >= lmax) continue;          // compile-time
                    v2f d0 = ccv[i][0] - wp[0][l];
                    v2f d1 = ccv[i][1] - wp[1][l];
                    v2f d2 = ccv[i][2] - wp[2][l];
                    v2f s  = d0 * d0;
                    s = __builtin_elementwise_fma(d1, d1, s);
                    s = __builtin_elementwise_fma(d2, d2, s);
                    v2f e;
                    e.x = __builtin_amdgcn_exp2f(-s.x);
                    e.y = __builtin_amdgcn_exp2f(-s.y);
                    float sax = fabsf(d0.x) + fabsf(d1.x);
                    sax += fabsf(d2.x);
                    float say = fabsf(d0.y) + fabsf(d1.y);
                    say += fabsf(d2.y);
                    t = __builtin_elementwise_fma(mk2(sax, say), e * glmv[l], t);
                }
                acc[i] = __builtin_elementwise_fma(t, mk2(rw, rw), acc[i]);
            }
        }
        v2f av = (acc[0] + acc[1]) + (acc[2] + acc[3]);
        a = av.x + av.y;
    } else {
        // ---- rim path: taps whose partner is out-of-image, counted once ----
        const int idx = blockIdx.x * 256 + tid;
        if (idx < NRIM_THREADS) {
            const int b = idx / RIM_PER_IMG;
            int r = idx - b * RIM_PER_IMG;
            int y, x;
            if (r < 3 * IMG_W) { y = r >> 9; x = r & (IMG_W - 1); }
            else if (r < 6 * IMG_W) { r -= 3 * IMG_W; y = (IMG_H - 3) + (r >> 9); x = r & (IMG_W - 1); }
            else if (r < 6 * IMG_W + 3 * (IMG_H - 6)) { r -= 6 * IMG_W; y = 3 + r / 3; x = r - 3 * (r / 3); }
            else { r -= 6 * IMG_W + 3 * (IMG_H - 6); y = 3 + r / 3; x = (IMG_W - 3) + (r - 3 * (r / 3)); }

            const float* base = in + (size_t)b * NC * IMG_H * IMG_W;
            const float cc0 = base[(0 * IMG_H + y) * IMG_W + x];
            const float cc1 = base[(1 * IMG_H + y) * IMG_W + x];
            const float cc2 = base[(2 * IMG_H + y) * IMG_W + x];

            #pragma unroll
            for (int k = 0; k < KS; ++k) {
                #pragma unroll
                for (int l = 0; l < KS; ++l) {
                    if (k == FR && l == FR) continue;
                    int qy = y + k - FR, qx = x + l - FR;
                    bool oob = ((unsigned)qy >= (unsigned)IMG_H) | ((unsigned)qx >= (unsigned)IMG_W);
                    if (oob) {
                        int ry = refl(qy, IMG_H), rx = refl(qx, IMG_W);
                        float v0 = base[(0 * IMG_H + ry) * IMG_W + rx];
                        float v1 = base[(1 * IMG_H + ry) * IMG_W + rx];
                        float v2 = base[(2 * IMG_H + ry) * IMG_W + rx];
                        float d0 = cc0 - v0, d1 = cc1 - v1, d2 = cc2 - v2;
                        float s = d0 * d0;
                        s = fmaf(d1, d1, s);
                        s = fmaf(d2, d2, s);
                        float e = __builtin_amdgcn_exp2f(-(K2F * s));
                        float sa = fabsf(d0) + fabsf(d1) + fabsf(d2);
                        a = fmaf(sa, e * (float)(g1d[k] * g1d[l] * INVN), a);
                    }
                }
            }
        }
        __syncthreads();
    }

    // Block reduction -> one partial per block.
    #pragma unroll
    for (int off = 32; off > 0; off >>= 1)
        a += __shfl_down(a, off, 64);
    if ((tid & 63) == 0) wsum[tid >> 6] = a;
    __syncthreads();
    if (tid == 0)
        partial[blockIdx.x] = wsum[0] + wsum[1] + wsum[2] + wsum[3];
}

__global__ __launch_bounds__(256) void finalize_kernel(const float* __restrict__ partial,
                                                       float* __restrict__ out) {
    __shared__ float wsum[4];
    const int tid = threadIdx.x;
    float a = 0.0f;
    for (int i = tid; i < NPART; i += 256) a += partial[i];
    #pragma unroll
    for (int off = 32; off > 0; off >>= 1)
        a += __shfl_down(a, off, 64);
    if ((tid & 63) == 0) wsum[tid >> 6] = a;
    __syncthreads();
    if (tid == 0)
        out[0] = (wsum[0] + wsum[1] + wsum[2] + wsum[3]) / (float)(NB * NC * IMG_H * IMG_W);
}

extern "C" void kernel_launch(void* const* d_in, const int* in_sizes, int n_in,
                              void* d_out, int out_size, void* d_ws, size_t ws_size,
                              hipStream_t stream) {
    const float* in = (const float*)d_in[0];
    float* out = (float*)d_out;
    float* ws  = (float*)d_ws;      // NPART partials; every slot written each call

    blt_fused<<<NBLK_A, 256, 0, stream>>>(in, ws);
    finalize_kernel<<<1, 256, 0, stream>>>(ws, out);
}